// Round 9
// baseline (261.765 us; speedup 1.0000x reference)
//
#include <hip/hip_runtime.h>
#include <math.h>

#define BB   4
#define CC   64
#define KK   64
#define DDim 16
#define HDim 64
#define WDim 64
#define SS   (DDim*HDim*WDim)   /* 65536 */
#define PLANE (HDim*WDim)       /* 4096  */
#define NCH1 256                /* gemm1 s-chunks per batch (chunk = 256) */
#define TOPN 6
#define RSTR 68                 /* ring row stride (pad 4: aligned, bank-spread) */

// ---------------------------------------------------------------------------
// Kernel 1: depthwise 3x3x3 conv (SAME), streaming 3-slot LDS ring.
// Block = (t, b, c): t=0 -> q (1 accumulator), t=1 -> k AND v (2 accs).
// grid = 2*4*64 = 512 blocks x 256 threads; walks d = 0..15.
// Ring: 3 slots x [64][68] f32 (52 KB -> 3 blocks/CU). Per step:
//   compute(d) from slots (d-1,d,d+1)%3 -> barrier -> SWRITE staged plane
//   d+2 into slot (d+2)%3 (just-freed) + SLOAD plane d+3 -> barrier.
// Rows are 16B-aligned; w-halos via __shfl from neighbor lanes. q-blocks
// compile a 1-acc body (no dead FMAs). Weights block-uniform -> SGPRs.
// ---------------------------------------------------------------------------
__global__ __launch_bounds__(256) void conv_ring2(
    const float* __restrict__ xq, const float* __restrict__ xkv,
    const float* __restrict__ wq, const float* __restrict__ bq,
    const float* __restrict__ wk, const float* __restrict__ bk,
    const float* __restrict__ wv, const float* __restrict__ bv,
    float* __restrict__ qout, float* __restrict__ kout, float* __restrict__ vout)
{
    __shared__ float ring[3][64*RSTR];

    // bijective XCD swizzle: 512 blocks / 8 XCDs = 64 contiguous per XCD
    int bid  = blockIdx.x;
    int work = (bid & 7) * 64 + (bid >> 3);
    int t = work >> 8;                         // 0: q, 1: k+v
    int b = (work >> 6) & 3;
    int c = work & 63;

    const float* src = (t ? xkv : xq) + (size_t)(b*CC + c) * SS;
    float wA[27], wB[27], bA, bB;
    if (t == 0) {
        #pragma unroll
        for (int i = 0; i < 27; ++i) { wA[i] = wq[c*27 + i]; wB[i] = 0.f; }
        bA = bq[c]; bB = 0.f;
    } else {
        #pragma unroll
        for (int i = 0; i < 27; ++i) { wA[i] = wk[c*27 + i]; wB[i] = wv[c*27 + i]; }
        bA = bk[c]; bB = bv[c];
    }
    float* dA = (t ? kout : qout) + (size_t)(b*CC + c) * SS;
    float* dB = vout + (size_t)(b*CC + c) * SS;

    const int tid  = threadIdx.x;
    const int lane = tid & 63;
    const int wq4  = tid & 3;
    const int w0   = wq4 << 4;                 // 0,16,32,48
    const int h    = tid >> 2;                 // 0..63
    const int trow = tid >> 4;                 // staging row base
    const int tc4  = tid & 15;                 // staging chunk

    float4 stg[4];
#define SLOAD(p) {                                                             \
    const float* ps_ = src + (size_t)(p)*PLANE;                                \
    _Pragma("unroll")                                                          \
    for (int i_ = 0; i_ < 4; ++i_)                                             \
        stg[i_] = *(const float4*)(ps_ + (i_*16 + trow)*64 + tc4*4); }
#define SWRITE(p) {                                                            \
    float* R_ = ring[(p) % 3];                                                 \
    _Pragma("unroll")                                                          \
    for (int i_ = 0; i_ < 4; ++i_)                                             \
        *(float4*)&R_[(i_*16 + trow)*RSTR + tc4*4] = stg[i_]; }

// per-plane compute body; DOB = 0/1 literal (dead-code elim for q blocks)
#define COMPUTE_D(dd, DOB) {                                                   \
    float accA[16], accB[16];                                                  \
    _Pragma("unroll")                                                          \
    for (int j = 0; j < 16; ++j) { accA[j] = bA; accB[j] = bB; }               \
    _Pragma("unroll")                                                          \
    for (int dz = 0; dz < 3; ++dz) {                                           \
        const int p = (dd) + dz - 1;                                           \
        if (p < 0 || p >= DDim) continue;      /* block-uniform */             \
        const float* R = ring[p % 3];                                          \
        _Pragma("unroll")                                                      \
        for (int dy = 0; dy < 3; ++dy) {                                       \
            const int gy = h + dy - 1;                                         \
            float r[18];                                                       \
            if (gy >= 0 && gy < HDim) {                                        \
                const float* rowp = &R[gy*RSTR + w0];                          \
                float4 a0 = *(const float4*)(rowp);                            \
                float4 a1 = *(const float4*)(rowp + 4);                        \
                float4 a2 = *(const float4*)(rowp + 8);                        \
                float4 a3 = *(const float4*)(rowp + 12);                       \
                r[1]=a0.x;  r[2]=a0.y;  r[3]=a0.z;  r[4]=a0.w;                 \
                r[5]=a1.x;  r[6]=a1.y;  r[7]=a1.z;  r[8]=a1.w;                 \
                r[9]=a2.x;  r[10]=a2.y; r[11]=a2.z; r[12]=a2.w;                \
                r[13]=a3.x; r[14]=a3.y; r[15]=a3.z; r[16]=a3.w;                \
            } else {                                                           \
                _Pragma("unroll")                                              \
                for (int j = 1; j <= 16; ++j) r[j] = 0.f;                      \
            }                                                                  \
            float lh = __shfl(r[16], lane - 1, 64);                            \
            float rh = __shfl(r[1],  lane + 1, 64);                            \
            r[0]  = wq4       ? lh : 0.f;                                      \
            r[17] = (wq4 < 3) ? rh : 0.f;                                      \
            const float ca0 = wA[dz*9 + dy*3 + 0];                             \
            const float ca1 = wA[dz*9 + dy*3 + 1];                             \
            const float ca2 = wA[dz*9 + dy*3 + 2];                             \
            const float cb0 = wB[dz*9 + dy*3 + 0];                             \
            const float cb1 = wB[dz*9 + dy*3 + 1];                             \
            const float cb2 = wB[dz*9 + dy*3 + 2];                             \
            _Pragma("unroll")                                                  \
            for (int j = 0; j < 16; ++j) {                                     \
                float sA = fmaf(ca0, r[j],   accA[j]);                         \
                sA       = fmaf(ca1, r[j+1], sA);                              \
                accA[j]  = fmaf(ca2, r[j+2], sA);                              \
                if (DOB) {                                                     \
                    float sB = fmaf(cb0, r[j],   accB[j]);                     \
                    sB       = fmaf(cb1, r[j+1], sB);                          \
                    accB[j]  = fmaf(cb2, r[j+2], sB);                          \
                }                                                              \
            }                                                                  \
        }                                                                      \
    }                                                                          \
    const int off = (dd)*PLANE + h*WDim + w0;                                  \
    *(float4*)&dA[off+0]  = make_float4(accA[0], accA[1], accA[2], accA[3]);   \
    *(float4*)&dA[off+4]  = make_float4(accA[4], accA[5], accA[6], accA[7]);   \
    *(float4*)&dA[off+8]  = make_float4(accA[8], accA[9], accA[10],accA[11]);  \
    *(float4*)&dA[off+12] = make_float4(accA[12],accA[13],accA[14],accA[15]);  \
    if (DOB) {                                                                 \
        *(float4*)&dB[off+0]  = make_float4(accB[0], accB[1], accB[2], accB[3]); \
        *(float4*)&dB[off+4]  = make_float4(accB[4], accB[5], accB[6], accB[7]); \
        *(float4*)&dB[off+8]  = make_float4(accB[8], accB[9], accB[10],accB[11]);\
        *(float4*)&dB[off+12] = make_float4(accB[12],accB[13],accB[14],accB[15]);\
    } }

    // prologue: slots <- p0, p1; regs <- p2
    SLOAD(0); SWRITE(0);
    SLOAD(1); SWRITE(1);
    SLOAD(2);
    __syncthreads();

    if (t == 0) {
        for (int d = 0; d < DDim; ++d) {
            COMPUTE_D(d, 0);
            __syncthreads();
            if (d + 2 < DDim) SWRITE(d + 2);
            if (d + 3 < DDim) SLOAD(d + 3);
            __syncthreads();
        }
    } else {
        for (int d = 0; d < DDim; ++d) {
            COMPUTE_D(d, 1);
            __syncthreads();
            if (d + 2 < DDim) SWRITE(d + 2);
            if (d + 3 < DDim) SLOAD(d + 3);
            __syncthreads();
        }
    }
#undef SLOAD
#undef SWRITE
#undef COMPUTE_D
}

// ---------------------------------------------------------------------------
// Kernel 2: attn partials. Per block: one batch, one 256-s chunk.
// LDS tiles stored [s][c] (pad 68) so inner loop reads are uniform-row
// ds_read_b128 (conflict-free broadcast groups). 128 threads, 4x8 per thread.
// ---------------------------------------------------------------------------
__global__ __launch_bounds__(128) void gemm1_qk(
    const float* __restrict__ q, const float* __restrict__ kk, float* __restrict__ part)
{
    __shared__ float qt[64][68];
    __shared__ float kt[64][68];
    int bid = blockIdx.x;
    int b  = bid >> 8;
    int ch = bid & 255;
    int tid = threadIdx.x;
    const float* qb = q  + (size_t)b*CC*SS;
    const float* kb = kk + (size_t)b*KK*SS;
    int c0  = (tid >> 3) * 4;     // 0..60
    int k0  = (tid & 7) * 8;      // 0..56
    int ls4 = (tid & 15) * 4;     // loader: s offset
    int lcg = tid >> 4;           // loader: c group 0..7
    float acc[4][8] = {};
    int sbase0 = ch * 256;
    for (int st = 0; st < 4; ++st) {
        int sb = sbase0 + st*64;
        __syncthreads();
        #pragma unroll
        for (int i = 0; i < 8; ++i) {
            int cc2 = lcg*8 + i;
            float4 qv = *(const float4*)&qb[cc2*SS + sb + ls4];
            float4 kv = *(const float4*)&kb[cc2*SS + sb + ls4];
            qt[ls4+0][cc2] = qv.x; qt[ls4+1][cc2] = qv.y; qt[ls4+2][cc2] = qv.z; qt[ls4+3][cc2] = qv.w;
            kt[ls4+0][cc2] = kv.x; kt[ls4+1][cc2] = kv.y; kt[ls4+2][cc2] = kv.z; kt[ls4+3][cc2] = kv.w;
        }
        __syncthreads();
        #pragma unroll 8
        for (int s = 0; s < 64; ++s) {
            float4 a  = *(const float4*)&qt[s][c0];
            float4 b0 = *(const float4*)&kt[s][k0];
            float4 b1 = *(const float4*)&kt[s][k0+4];
            float av[4] = {a.x, a.y, a.z, a.w};
            float bv[8] = {b0.x,b0.y,b0.z,b0.w,b1.x,b1.y,b1.z,b1.w};
            #pragma unroll
            for (int i = 0; i < 4; ++i)
                #pragma unroll
                for (int j = 0; j < 8; ++j)
                    acc[i][j] = fmaf(av[i], bv[j], acc[i][j]);
        }
    }
    float* pb = part + (size_t)(b*NCH1 + ch)*(CC*KK);
    #pragma unroll
    for (int i = 0; i < 4; ++i) {
        *(float4*)&pb[(c0+i)*KK + k0]     = make_float4(acc[i][0],acc[i][1],acc[i][2],acc[i][3]);
        *(float4*)&pb[(c0+i)*KK + k0 + 4] = make_float4(acc[i][4],acc[i][5],acc[i][6],acc[i][7]);
    }
}

// ---------------------------------------------------------------------------
// Kernel 3: reduce 256 chunk-partials -> attn logits (scaled 1/sqrt(K)=0.125)
// ---------------------------------------------------------------------------
__global__ __launch_bounds__(256) void reduce_attn(
    const float* __restrict__ part, float* __restrict__ attn)
{
    int bid = blockIdx.x;            // b*64 + c
    int b = bid >> 6, c = bid & 63;
    int tid = threadIdx.x;
    int k = tid & 63, g = tid >> 6;
    float s = 0.f;
    for (int ch = g; ch < NCH1; ch += 4)
        s += part[(size_t)(b*NCH1 + ch)*(CC*KK) + c*KK + k];
    __shared__ float red[256];
    red[tid] = s;
    __syncthreads();
    if (tid < 64) {
        float tot = red[tid] + red[tid+64] + red[tid+128] + red[tid+192];
        attn[b*CC*KK + c*KK + tid] = tot * 0.125f;
    }
}

// ---------------------------------------------------------------------------
// Kernel 4: per-batch softmax over K (rows) + top-6 mask per column over C.
// Strict ">" selection == lax.top_k lowest-index-first tie break. Writes
// attn_m (output 1) which gemm2 consumes.
// ---------------------------------------------------------------------------
__global__ __launch_bounds__(64) void softmax_topk(
    const float* __restrict__ attn, float* __restrict__ attn_m)
{
    __shared__ float p[64*65];
    int b = blockIdx.x;
    int t = threadIdx.x;
    for (int i = 0; i < 64; ++i) p[i*65 + t] = attn[b*4096 + i*64 + t];
    __syncthreads();
    // row softmax (row = t)
    float m = -1e30f;
    for (int k = 0; k < 64; ++k) m = fmaxf(m, p[t*65 + k]);
    float sum = 0.f;
    for (int k = 0; k < 64; ++k) { float e = expf(p[t*65+k] - m); p[t*65+k] = e; sum += e; }
    float inv = 1.f / sum;
    for (int k = 0; k < 64; ++k) p[t*65+k] *= inv;
    __syncthreads();
    // top-6 per column (column = t)
    unsigned long long chosen = 0ull;
    #pragma unroll
    for (int pass = 0; pass < TOPN; ++pass) {
        float best = -1.f; int bi = 0;
        for (int c2 = 0; c2 < 64; ++c2) {
            float v = p[c2*65 + t];
            if (!((chosen >> c2) & 1ull) && v > best) { best = v; bi = c2; }
        }
        chosen |= 1ull << bi;
    }
    for (int c2 = 0; c2 < 64; ++c2) {
        float v = p[c2*65 + t];
        attn_m[b*4096 + c2*64 + t] = ((chosen >> c2) & 1ull) ? v : 0.f;
    }
}

// ---------------------------------------------------------------------------
// Kernel 5: out = x_q + attn_m @ v. Per block: one batch, 512-s chunk
// (4 subtiles of 128). attn_m held transposed [k][c] in LDS for b128 reads.
// ---------------------------------------------------------------------------
__global__ __launch_bounds__(256) void gemm2_out(
    const float* __restrict__ attn_m, const float* __restrict__ v,
    const float* __restrict__ xq, float* __restrict__ out)
{
    __shared__ float amt[64][68];    // [k][c]
    __shared__ float vt[64][132];    // [k][s]
    int bid = blockIdx.x;
    int b  = bid >> 7;
    int ch = bid & 127;
    int tid = threadIdx.x;
    for (int i = 0; i < 16; ++i) {
        int idx = i*256 + tid;                 // idx = c*64 + k
        amt[idx & 63][idx >> 6] = attn_m[b*4096 + idx];
    }
    int c0 = (tid >> 4) * 4;      // 0..60
    int s0 = (tid & 15) * 8;      // 0..120
    const float* vb = v  + (size_t)b*KK*SS;
    const float* xb = xq + (size_t)b*CC*SS;
    float* ob = out + (size_t)b*CC*SS;
    int sb0 = ch * 512;
    for (int st = 0; st < 4; ++st) {
        int sb = sb0 + st*128;
        __syncthreads();
        #pragma unroll
        for (int i = 0; i < 8; ++i) {
            int k  = (tid >> 5)*8 + i;
            int s4 = (tid & 31)*4;
            *(float4*)&vt[k][s4] = *(const float4*)&vb[k*SS + sb + s4];
        }
        __syncthreads();
        float acc[4][8] = {};
        #pragma unroll 8
        for (int k = 0; k < 64; ++k) {
            float4 a  = *(const float4*)&amt[k][c0];
            float4 v0 = *(const float4*)&vt[k][s0];
            float4 v1 = *(const float4*)&vt[k][s0+4];
            float av[4] = {a.x,a.y,a.z,a.w};
            float vv[8] = {v0.x,v0.y,v0.z,v0.w,v1.x,v1.y,v1.z,v1.w};
            #pragma unroll
            for (int i = 0; i < 4; ++i)
                #pragma unroll
                for (int j = 0; j < 8; ++j)
                    acc[i][j] = fmaf(av[i], vv[j], acc[i][j]);
        }
        #pragma unroll
        for (int i = 0; i < 4; ++i) {
            int off = (c0+i)*SS + sb + s0;
            float4 x0 = *(const float4*)&xb[off];
            float4 x1 = *(const float4*)&xb[off+4];
            *(float4*)&ob[off]   = make_float4(acc[i][0]+x0.x, acc[i][1]+x0.y,
                                               acc[i][2]+x0.z, acc[i][3]+x0.w);
            *(float4*)&ob[off+4] = make_float4(acc[i][4]+x1.x, acc[i][5]+x1.y,
                                               acc[i][6]+x1.z, acc[i][7]+x1.w);
        }
    }
}

// ---------------------------------------------------------------------------
extern "C" void kernel_launch(void* const* d_in, const int* in_sizes, int n_in,
                              void* d_out, int out_size, void* d_ws, size_t ws_size,
                              hipStream_t stream)
{
    const float* xq  = (const float*)d_in[0];
    const float* xkv = (const float*)d_in[1];
    const float* wq  = (const float*)d_in[2];
    const float* bq  = (const float*)d_in[3];
    const float* wk  = (const float*)d_in[4];
    const float* bk  = (const float*)d_in[5];
    const float* wv  = (const float*)d_in[6];
    const float* bv  = (const float*)d_in[7];
    float* out = (float*)d_out;

    // workspace: k, v, gemm1 partials, attn logits  (~145 MiB)
    float* k_ws = (float*)d_ws;
    float* v_ws = k_ws + (size_t)BB*KK*SS;
    float* part = v_ws + (size_t)BB*KK*SS;
    float* attn = part + (size_t)BB*NCH1*CC*KK;

    float* q_store = out;                        // q lives in output-0 region,
                                                 // overwritten by gemm2_out
    float* attn_m  = out + (size_t)BB*CC*SS;     // output 1 (B*C*K floats)

    conv_ring2 <<<2*BB*CC,   256, 0, stream>>>(xq, xkv, wq, bq, wk, bk, wv, bv,
                                               q_store, k_ws, v_ws);
    gemm1_qk   <<<BB*NCH1,   128, 0, stream>>>(q_store, k_ws, part);
    reduce_attn<<<BB*CC,     256, 0, stream>>>(part, attn);
    softmax_topk<<<BB,        64, 0, stream>>>(attn, attn_m);
    gemm2_out  <<<BB*128,    256, 0, stream>>>(attn_m, v_ws, xq, out);
}

// Round 10
// 216.840 us; speedup vs baseline: 1.2072x; 1.2072x over previous
//
#include <hip/hip_runtime.h>
#include <math.h>

#define BB   4
#define CC   64
#define KK   64
#define DDim 16
#define HDim 64
#define WDim 64
#define SS   (DDim*HDim*WDim)   /* 65536 */
#define PLANE (HDim*WDim)       /* 4096  */
#define NCH1 256                /* gemm1 s-chunks per batch (chunk = 256) */
#define TOPN 6
#define RSTR 68                 /* ring row stride (pad 4) */
#define RROWS 34                /* 32 output rows + 2 halo rows per slot */

// ---------------------------------------------------------------------------
// Kernel 1: depthwise 3x3x3 conv (SAME), streaming 4-slot half-plane ring.
// Block = (t, b, c, hh): t=0 -> q (1 acc), t=1 -> k AND v (2 accs);
// hh = h-half (rows 0..31 / 32..63). grid = 2*4*64*2 = 1024 x 256 threads.
// Ring: 4 slots x [34][68] f32 = 37 KB -> 4 blocks/CU (16 waves).
// Slot for plane p holds rows g0-1 .. g0+32 (edge rows pre-zeroed), so the
// compute body is branch-free. Schedule per step d (ONE barrier):
//   SLOAD(d+2) into regs (issue early) -> COMPUTE(d) from slots
//   (d-1,d,d+1) -> SWRITE(d+2) into slot (d+2)%4 (disjoint) -> barrier.
// w-halos via __shfl; weights block-uniform -> SGPRs.
// ---------------------------------------------------------------------------
__global__ __launch_bounds__(256) void conv_hs(
    const float* __restrict__ xq, const float* __restrict__ xkv,
    const float* __restrict__ wq, const float* __restrict__ bq,
    const float* __restrict__ wk, const float* __restrict__ bk,
    const float* __restrict__ wv, const float* __restrict__ bv,
    float* __restrict__ qout, float* __restrict__ kout, float* __restrict__ vout)
{
    __shared__ float ring[4][RROWS*RSTR];      // 36.99 KB

    // bijective XCD swizzle: 1024 blocks / 8 XCDs = 128 contiguous per XCD;
    // consecutive works = hh pairs of one (b,c) -> L2 halo/dz reuse
    int bid  = blockIdx.x;
    int work = (bid & 7) * 128 + (bid >> 3);
    int t  = work >> 9;                        // 0: q, 1: k+v
    int b  = (work >> 7) & 3;
    int c  = (work >> 1) & 63;
    int hh = work & 1;
    int g0 = hh << 5;                          // first output row

    const float* src = (t ? xkv : xq) + (size_t)(b*CC + c) * SS;
    float wA[27], wB[27], bA, bB;
    if (t == 0) {
        #pragma unroll
        for (int i = 0; i < 27; ++i) { wA[i] = wq[c*27 + i]; wB[i] = 0.f; }
        bA = bq[c]; bB = 0.f;
    } else {
        #pragma unroll
        for (int i = 0; i < 27; ++i) { wA[i] = wk[c*27 + i]; wB[i] = wv[c*27 + i]; }
        bA = bk[c]; bB = bv[c];
    }
    float* dA = (t ? kout : qout) + (size_t)(b*CC + c) * SS;
    float* dB = vout + (size_t)(b*CC + c) * SS;

    const int tid  = threadIdx.x;
    const int lane = tid & 63;
    const int wg   = tid & 7;                  // w-group (8 wide)
    const int w0   = wg << 3;                  // 0..56
    const int hl   = tid >> 3;                 // 0..31 (local output row)

    // staging: 34 rows x 64 floats = 544 float4; threads cover fidx<544
    float4 stg[3];
#define SLOAD(p) {                                                             \
    const int p_ = (p);                                                        \
    if (p_ >= 0 && p_ < DDim) {                                                \
        const float* ps_ = src + (size_t)p_*PLANE;                             \
        _Pragma("unroll")                                                      \
        for (int i_ = 0; i_ < 3; ++i_) {                                       \
            const int fidx_ = i_*256 + tid;                                    \
            const int gy_   = g0 - 1 + (fidx_ >> 4);                           \
            float4 v_ = make_float4(0.f,0.f,0.f,0.f);                          \
            if (fidx_ < 544 && gy_ >= 0 && gy_ < HDim)                         \
                v_ = *(const float4*)(ps_ + gy_*WDim + (fidx_ & 15)*4);        \
            stg[i_] = v_;                                                      \
        }                                                                      \
    } else {                                                                   \
        _Pragma("unroll")                                                      \
        for (int i_ = 0; i_ < 3; ++i_) stg[i_] = make_float4(0.f,0.f,0.f,0.f); \
    } }
#define SWRITE(p) {                                                            \
    float* R_ = ring[((p) + 4) & 3];                                           \
    _Pragma("unroll")                                                          \
    for (int i_ = 0; i_ < 3; ++i_) {                                           \
        const int fidx_ = i_*256 + tid;                                        \
        if (fidx_ < 544)                                                       \
            *(float4*)&R_[(fidx_ >> 4)*RSTR + (fidx_ & 15)*4] = stg[i_];       \
    } }

// branch-free compute of plane dd; DOB = 0/1 literal
#define COMPUTE_D(dd, DOB) {                                                   \
    float accA[8], accB[8];                                                    \
    _Pragma("unroll")                                                          \
    for (int j = 0; j < 8; ++j) { accA[j] = bA; accB[j] = bB; }                \
    _Pragma("unroll")                                                          \
    for (int dz = 0; dz < 3; ++dz) {                                           \
        const float* R = ring[((dd) + dz + 3) & 3];   /* plane dd+dz-1 */      \
        _Pragma("unroll")                                                      \
        for (int dy = 0; dy < 3; ++dy) {                                       \
            const float* rowp = &R[(hl + dy)*RSTR + w0];                       \
            float4 a0 = *(const float4*)(rowp);                                \
            float4 a1 = *(const float4*)(rowp + 4);                            \
            float r[10];                                                       \
            r[1]=a0.x; r[2]=a0.y; r[3]=a0.z; r[4]=a0.w;                        \
            r[5]=a1.x; r[6]=a1.y; r[7]=a1.z; r[8]=a1.w;                        \
            float lh = __shfl(r[8], lane - 1, 64);                             \
            float rh = __shfl(r[1], lane + 1, 64);                             \
            r[0] = wg       ? lh : 0.f;                                        \
            r[9] = (wg < 7) ? rh : 0.f;                                        \
            const float ca0 = wA[dz*9 + dy*3 + 0];                             \
            const float ca1 = wA[dz*9 + dy*3 + 1];                             \
            const float ca2 = wA[dz*9 + dy*3 + 2];                             \
            const float cb0 = wB[dz*9 + dy*3 + 0];                             \
            const float cb1 = wB[dz*9 + dy*3 + 1];                             \
            const float cb2 = wB[dz*9 + dy*3 + 2];                             \
            _Pragma("unroll")                                                  \
            for (int j = 0; j < 8; ++j) {                                      \
                float sA = fmaf(ca0, r[j],   accA[j]);                         \
                sA       = fmaf(ca1, r[j+1], sA);                              \
                accA[j]  = fmaf(ca2, r[j+2], sA);                              \
                if (DOB) {                                                     \
                    float sB = fmaf(cb0, r[j],   accB[j]);                     \
                    sB       = fmaf(cb1, r[j+1], sB);                          \
                    accB[j]  = fmaf(cb2, r[j+2], sB);                          \
                }                                                              \
            }                                                                  \
        }                                                                      \
    }                                                                          \
    const int off = (dd)*PLANE + (g0 + hl)*WDim + w0;                          \
    *(float4*)&dA[off]   = make_float4(accA[0],accA[1],accA[2],accA[3]);       \
    *(float4*)&dA[off+4] = make_float4(accA[4],accA[5],accA[6],accA[7]);       \
    if (DOB) {                                                                 \
        *(float4*)&dB[off]   = make_float4(accB[0],accB[1],accB[2],accB[3]);   \
        *(float4*)&dB[off+4] = make_float4(accB[4],accB[5],accB[6],accB[7]);   \
    } }

    // prologue: slots <- planes -1 (zeros), 0, 1
    SLOAD(-1); SWRITE(-1);
    SLOAD(0);  SWRITE(0);
    SLOAD(1);  SWRITE(1);
    __syncthreads();

    if (t == 0) {
        for (int d = 0; d < DDim; ++d) {
            if (d < DDim - 1) SLOAD(d + 2);    // issue early (zeros if p==16)
            COMPUTE_D(d, 0);
            if (d < DDim - 1) SWRITE(d + 2);   // slot (d+2)%4 disjoint
            __syncthreads();
        }
    } else {
        for (int d = 0; d < DDim; ++d) {
            if (d < DDim - 1) SLOAD(d + 2);
            COMPUTE_D(d, 1);
            if (d < DDim - 1) SWRITE(d + 2);
            __syncthreads();
        }
    }
#undef SLOAD
#undef SWRITE
#undef COMPUTE_D
}

// ---------------------------------------------------------------------------
// Kernel 2: attn partials. Per block: one batch, one 256-s chunk.
// LDS tiles stored [s][c] (pad 68) so inner loop reads are uniform-row
// ds_read_b128 (conflict-free broadcast groups). 128 threads, 4x8 per thread.
// ---------------------------------------------------------------------------
__global__ __launch_bounds__(128) void gemm1_qk(
    const float* __restrict__ q, const float* __restrict__ kk, float* __restrict__ part)
{
    __shared__ float qt[64][68];
    __shared__ float kt[64][68];
    int bid = blockIdx.x;
    int b  = bid >> 8;
    int ch = bid & 255;
    int tid = threadIdx.x;
    const float* qb = q  + (size_t)b*CC*SS;
    const float* kb = kk + (size_t)b*KK*SS;
    int c0  = (tid >> 3) * 4;     // 0..60
    int k0  = (tid & 7) * 8;      // 0..56
    int ls4 = (tid & 15) * 4;     // loader: s offset
    int lcg = tid >> 4;           // loader: c group 0..7
    float acc[4][8] = {};
    int sbase0 = ch * 256;
    for (int st = 0; st < 4; ++st) {
        int sb = sbase0 + st*64;
        __syncthreads();
        #pragma unroll
        for (int i = 0; i < 8; ++i) {
            int cc2 = lcg*8 + i;
            float4 qv = *(const float4*)&qb[cc2*SS + sb + ls4];
            float4 kv = *(const float4*)&kb[cc2*SS + sb + ls4];
            qt[ls4+0][cc2] = qv.x; qt[ls4+1][cc2] = qv.y; qt[ls4+2][cc2] = qv.z; qt[ls4+3][cc2] = qv.w;
            kt[ls4+0][cc2] = kv.x; kt[ls4+1][cc2] = kv.y; kt[ls4+2][cc2] = kv.z; kt[ls4+3][cc2] = kv.w;
        }
        __syncthreads();
        #pragma unroll 8
        for (int s = 0; s < 64; ++s) {
            float4 a  = *(const float4*)&qt[s][c0];
            float4 b0 = *(const float4*)&kt[s][k0];
            float4 b1 = *(const float4*)&kt[s][k0+4];
            float av[4] = {a.x, a.y, a.z, a.w};
            float bv[8] = {b0.x,b0.y,b0.z,b0.w,b1.x,b1.y,b1.z,b1.w};
            #pragma unroll
            for (int i = 0; i < 4; ++i)
                #pragma unroll
                for (int j = 0; j < 8; ++j)
                    acc[i][j] = fmaf(av[i], bv[j], acc[i][j]);
        }
    }
    float* pb = part + (size_t)(b*NCH1 + ch)*(CC*KK);
    #pragma unroll
    for (int i = 0; i < 4; ++i) {
        *(float4*)&pb[(c0+i)*KK + k0]     = make_float4(acc[i][0],acc[i][1],acc[i][2],acc[i][3]);
        *(float4*)&pb[(c0+i)*KK + k0 + 4] = make_float4(acc[i][4],acc[i][5],acc[i][6],acc[i][7]);
    }
}

// ---------------------------------------------------------------------------
// Kernel 3: reduce 256 chunk-partials -> attn logits (scaled 1/sqrt(K)=0.125)
// ---------------------------------------------------------------------------
__global__ __launch_bounds__(256) void reduce_attn(
    const float* __restrict__ part, float* __restrict__ attn)
{
    int bid = blockIdx.x;            // b*64 + c
    int b = bid >> 6, c = bid & 63;
    int tid = threadIdx.x;
    int k = tid & 63, g = tid >> 6;
    float s = 0.f;
    for (int ch = g; ch < NCH1; ch += 4)
        s += part[(size_t)(b*NCH1 + ch)*(CC*KK) + c*KK + k];
    __shared__ float red[256];
    red[tid] = s;
    __syncthreads();
    if (tid < 64) {
        float tot = red[tid] + red[tid+64] + red[tid+128] + red[tid+192];
        attn[b*CC*KK + c*KK + tid] = tot * 0.125f;
    }
}

// ---------------------------------------------------------------------------
// Kernel 4: per-batch softmax over K (rows) + top-6 mask per column over C.
// Strict ">" selection == lax.top_k lowest-index-first tie break. Writes
// attn_m (output 1) which gemm2 consumes.
// ---------------------------------------------------------------------------
__global__ __launch_bounds__(64) void softmax_topk(
    const float* __restrict__ attn, float* __restrict__ attn_m)
{
    __shared__ float p[64*65];
    int b = blockIdx.x;
    int t = threadIdx.x;
    for (int i = 0; i < 64; ++i) p[i*65 + t] = attn[b*4096 + i*64 + t];
    __syncthreads();
    // row softmax (row = t)
    float m = -1e30f;
    for (int k = 0; k < 64; ++k) m = fmaxf(m, p[t*65 + k]);
    float sum = 0.f;
    for (int k = 0; k < 64; ++k) { float e = expf(p[t*65+k] - m); p[t*65+k] = e; sum += e; }
    float inv = 1.f / sum;
    for (int k = 0; k < 64; ++k) p[t*65+k] *= inv;
    __syncthreads();
    // top-6 per column (column = t)
    unsigned long long chosen = 0ull;
    #pragma unroll
    for (int pass = 0; pass < TOPN; ++pass) {
        float best = -1.f; int bi = 0;
        for (int c2 = 0; c2 < 64; ++c2) {
            float v = p[c2*65 + t];
            if (!((chosen >> c2) & 1ull) && v > best) { best = v; bi = c2; }
        }
        chosen |= 1ull << bi;
    }
    for (int c2 = 0; c2 < 64; ++c2) {
        float v = p[c2*65 + t];
        attn_m[b*4096 + c2*64 + t] = ((chosen >> c2) & 1ull) ? v : 0.f;
    }
}

// ---------------------------------------------------------------------------
// Kernel 5: out = x_q + attn_m @ v. Per block: one batch, 512-s chunk
// (4 subtiles of 128). attn_m held transposed [k][c] in LDS for b128 reads.
// ---------------------------------------------------------------------------
__global__ __launch_bounds__(256) void gemm2_out(
    const float* __restrict__ attn_m, const float* __restrict__ v,
    const float* __restrict__ xq, float* __restrict__ out)
{
    __shared__ float amt[64][68];    // [k][c]
    __shared__ float vt[64][132];    // [k][s]
    int bid = blockIdx.x;
    int b  = bid >> 7;
    int ch = bid & 127;
    int tid = threadIdx.x;
    for (int i = 0; i < 16; ++i) {
        int idx = i*256 + tid;                 // idx = c*64 + k
        amt[idx & 63][idx >> 6] = attn_m[b*4096 + idx];
    }
    int c0 = (tid >> 4) * 4;      // 0..60
    int s0 = (tid & 15) * 8;      // 0..120
    const float* vb = v  + (size_t)b*KK*SS;
    const float* xb = xq + (size_t)b*CC*SS;
    float* ob = out + (size_t)b*CC*SS;
    int sb0 = ch * 512;
    for (int st = 0; st < 4; ++st) {
        int sb = sb0 + st*128;
        __syncthreads();
        #pragma unroll
        for (int i = 0; i < 8; ++i) {
            int k  = (tid >> 5)*8 + i;
            int s4 = (tid & 31)*4;
            *(float4*)&vt[k][s4] = *(const float4*)&vb[k*SS + sb + s4];
        }
        __syncthreads();
        float acc[4][8] = {};
        #pragma unroll 8
        for (int k = 0; k < 64; ++k) {
            float4 a  = *(const float4*)&amt[k][c0];
            float4 v0 = *(const float4*)&vt[k][s0];
            float4 v1 = *(const float4*)&vt[k][s0+4];
            float av[4] = {a.x,a.y,a.z,a.w};
            float vv[8] = {v0.x,v0.y,v0.z,v0.w,v1.x,v1.y,v1.z,v1.w};
            #pragma unroll
            for (int i = 0; i < 4; ++i)
                #pragma unroll
                for (int j = 0; j < 8; ++j)
                    acc[i][j] = fmaf(av[i], vv[j], acc[i][j]);
        }
        #pragma unroll
        for (int i = 0; i < 4; ++i) {
            int off = (c0+i)*SS + sb + s0;
            float4 x0 = *(const float4*)&xb[off];
            float4 x1 = *(const float4*)&xb[off+4];
            *(float4*)&ob[off]   = make_float4(acc[i][0]+x0.x, acc[i][1]+x0.y,
                                               acc[i][2]+x0.z, acc[i][3]+x0.w);
            *(float4*)&ob[off+4] = make_float4(acc[i][4]+x1.x, acc[i][5]+x1.y,
                                               acc[i][6]+x1.z, acc[i][7]+x1.w);
        }
    }
}

// ---------------------------------------------------------------------------
extern "C" void kernel_launch(void* const* d_in, const int* in_sizes, int n_in,
                              void* d_out, int out_size, void* d_ws, size_t ws_size,
                              hipStream_t stream)
{
    const float* xq  = (const float*)d_in[0];
    const float* xkv = (const float*)d_in[1];
    const float* wq  = (const float*)d_in[2];
    const float* bq  = (const float*)d_in[3];
    const float* wk  = (const float*)d_in[4];
    const float* bk  = (const float*)d_in[5];
    const float* wv  = (const float*)d_in[6];
    const float* bv  = (const float*)d_in[7];
    float* out = (float*)d_out;

    // workspace: k, v, gemm1 partials, attn logits  (~145 MiB)
    float* k_ws = (float*)d_ws;
    float* v_ws = k_ws + (size_t)BB*KK*SS;
    float* part = v_ws + (size_t)BB*KK*SS;
    float* attn = part + (size_t)BB*NCH1*CC*KK;

    float* q_store = out;                        // q lives in output-0 region,
                                                 // overwritten by gemm2_out
    float* attn_m  = out + (size_t)BB*CC*SS;     // output 1 (B*C*K floats)

    conv_hs    <<<2*BB*CC*2, 256, 0, stream>>>(xq, xkv, wq, bq, wk, bk, wv, bv,
                                               q_store, k_ws, v_ws);
    gemm1_qk   <<<BB*NCH1,   128, 0, stream>>>(q_store, k_ws, part);
    reduce_attn<<<BB*CC,     256, 0, stream>>>(part, attn);
    softmax_topk<<<BB,        64, 0, stream>>>(attn, attn_m);
    gemm2_out  <<<BB*128,    256, 0, stream>>>(attn_m, v_ws, xq, out);
}